// Round 1
// 361.573 us; speedup vs baseline: 1.1346x; 1.1346x over previous
//
#include <hip/hip_runtime.h>
#include <hip/hip_bf16.h>
#include <stdint.h>

#define T_LEN   16384
#define HID     1024
#define KDIM    1024
#define CHUNK   64
#define NCHUNK  256   // T_LEN / CHUNK

typedef __bf16 bf16x8 __attribute__((ext_vector_type(8)));
typedef float  f32x4  __attribute__((ext_vector_type(4)));

__device__ inline ushort f2bf(float f) {
  union { float f; uint32_t u; } v; v.f = f;
  uint32_t r = v.u + 0x7FFF + ((v.u >> 16) & 1);   // RNE
  return (ushort)(r >> 16);
}
__device__ inline float bf2f(ushort u) {
  union { uint32_t u; float f; } v; v.u = ((uint32_t)u) << 16;
  return v.f;
}

__device__ inline void gload16(const void* g, void* l) {
  __builtin_amdgcn_global_load_lds(
      (const __attribute__((address_space(1))) void*)g,
      (__attribute__((address_space(3))) void*)l, 16, 0, 0);
}

// ---------------- prep: lambda (complex), exp(gamma) ----------------
__global__ __launch_bounds__(256) void prep_kernel(
    const float* __restrict__ nu_log, const float* __restrict__ theta_log,
    const float* __restrict__ gamma_log,
    float* __restrict__ lam_re, float* __restrict__ lam_im, float* __restrict__ eg) {
  int h = blockIdx.x * 256 + threadIdx.x;
  if (h < HID) {
    float mag = expf(-expf(nu_log[h]));
    float th  = expf(theta_log[h]);
    lam_re[h] = mag * cosf(th);
    lam_im[h] = mag * sinf(th);
    eg[h]     = expf(gamma_log[h]);
  }
}

// ---------------- fp32 -> bf16, vectorized x4 ----------------
__global__ __launch_bounds__(256) void convX(
    const float* __restrict__ src, ushort* __restrict__ dst) {
  size_t i = ((size_t)blockIdx.x * 256 + threadIdx.x) * 4;
  float4 v = *(const float4*)(src + i);
  ushort4 o;
  o.x = f2bf(v.x); o.y = f2bf(v.y); o.z = f2bf(v.z); o.w = f2bf(v.w);
  *(ushort4*)(dst + i) = o;
}

// ---------------- all weight prep in one kernel (z selects job) ----------------
__global__ __launch_bounds__(256) void weight_prep(
    const float* __restrict__ Bre, const float* __restrict__ Bim,
    const float* __restrict__ Cre, const float* __restrict__ Cim,
    const float* __restrict__ D,   const float* __restrict__ eg,
    ushort* __restrict__ BreT, ushort* __restrict__ BimT,
    ushort* __restrict__ CreB, ushort* __restrict__ CimB,
    ushort* __restrict__ DT) {
  __shared__ float tile[32][33];
  int z = blockIdx.z;
  if (z == 2 || z == 3) {
    const float* src = (z == 2) ? Cre : Cim;
    ushort* dst = (z == 2) ? CreB : CimB;
    float s = (z == 2) ? 1.0f : -1.0f;
    size_t base = ((size_t)blockIdx.y * 32 + (threadIdx.x >> 3)) * 1024 +
                  blockIdx.x * 32 + (threadIdx.x & 7) * 4;
    float4 v = *(const float4*)(src + base);
    ushort4 o;
    o.x = f2bf(v.x * s); o.y = f2bf(v.y * s);
    o.z = f2bf(v.z * s); o.w = f2bf(v.w * s);
    *(ushort4*)(dst + base) = o;
    return;
  }
  const float* src = (z == 0) ? Bre : (z == 1) ? Bim : D;
  ushort* dst = (z == 0) ? BreT : (z == 1) ? BimT : DT;
  bool scaled = (z < 2);
  int bx = blockIdx.x * 32;   // n-block
  int by = blockIdx.y * 32;   // k-block
  int tx = threadIdx.x & 31, ty = threadIdx.x >> 5;
#pragma unroll
  for (int r = 0; r < 32; r += 8)
    tile[ty + r][tx] = src[(size_t)(by + ty + r) * 1024 + bx + tx];
  __syncthreads();
  float sc = scaled ? eg[by + tx] : 1.0f;
#pragma unroll
  for (int r = 0; r < 32; r += 8)
    dst[(size_t)(bx + ty + r) * 1024 + by + tx] = f2bf(tile[tx][ty + r] * sc);
}

// ================= 256x256 8-phase MFMA GEMM (T1+T2+T3/T4+T5) =================
// 512 threads = 8 waves (2 M x 4 N). Per-wave output 128x64.
// LDS: A dbuf 2x[256][64] + B dbuf 2x[256][64] bf16 = 128 KiB.
// Swizzle: byte ^= (row&7)<<4, same involution on gload source and ds_read.

#define BAR()   __builtin_amdgcn_s_barrier()
#define SCH0()  __builtin_amdgcn_sched_barrier(0)
#define LGKM0() asm volatile("s_waitcnt lgkmcnt(0)")
#define VM4()   asm volatile("s_waitcnt vmcnt(4)")
#define VM0()   asm volatile("s_waitcnt vmcnt(0)")

#define STAGE_HALF(G, LDA, R0, K0, LT, HALF)                         \
  do {                                                               \
    _Pragma("unroll")                                                \
    for (int is_ = 0; is_ < 2; ++is_) {                              \
      int seg_ = w * 2 + is_;                                        \
      int gr_ = (R0) + (HALF) * 128 + seg_ * 8 + (l >> 3);           \
      int gc_ = (K0) + (((l & 7) ^ (l >> 3)) << 3);                  \
      gload16((G) + (size_t)gr_ * (LDA) + gc_,                       \
              (LT) + (HALF) * 8192 + seg_ * 512);                    \
    }                                                                \
  } while (0)

#define DS_A(QM, BUF)                                                \
  do {                                                               \
    _Pragma("unroll")                                                \
    for (int m_ = 0; m_ < 4; ++m_) {                                 \
      int r_ = (wr * 128 + ((QM) * 4 + m_) * 16 + lo) * 64;          \
      a[m_][0] = *(const bf16x8*)((BUF) + r_ + c0us);                \
      a[m_][1] = *(const bf16x8*)((BUF) + r_ + c1us);                \
    }                                                                \
  } while (0)

#define DS_B(QN, BUF, REG)                                           \
  do {                                                               \
    _Pragma("unroll")                                                \
    for (int n_ = 0; n_ < 2; ++n_) {                                 \
      int r_ = (wc * 64 + ((QN) * 2 + n_) * 16 + lo) * 64;           \
      REG[n_][0] = *(const bf16x8*)((BUF) + r_ + c0us);              \
      REG[n_][1] = *(const bf16x8*)((BUF) + r_ + c1us);              \
    }                                                                \
  } while (0)

#define MFMA_Q(QM, QN, REG)                                          \
  do {                                                               \
    __builtin_amdgcn_s_setprio(1);                                   \
    _Pragma("unroll")                                                \
    for (int m_ = 0; m_ < 4; ++m_)                                   \
      _Pragma("unroll")                                              \
      for (int n_ = 0; n_ < 2; ++n_) {                               \
        f32x4* ac_ = &acc[(QM) * 4 + m_][(QN) * 2 + n_];             \
        *ac_ = __builtin_amdgcn_mfma_f32_16x16x32_bf16(              \
            a[m_][0], REG[n_][0], *ac_, 0, 0, 0);                    \
        *ac_ = __builtin_amdgcn_mfma_f32_16x16x32_bf16(              \
            a[m_][1], REG[n_][1], *ac_, 0, 0, 0);                    \
      }                                                              \
    __builtin_amdgcn_s_setprio(0);                                   \
  } while (0)

// K is fixed 1024 (NT=16 k-tiles of 64, 8 iterations x 8 phases).
__device__ __forceinline__ void gemm256_seg(
    const ushort* __restrict__ A, int lda, const ushort* __restrict__ B,
    ushort* lds, int row0, int col0,
    int w, int l, int wr, int wc, int lo, int q, int c0us, int c1us,
    f32x4 acc[8][4]) {
  ushort* A0 = lds;
  ushort* A1 = lds + 16384;
  ushort* B0 = lds + 32768;
  ushort* B1 = lds + 49152;
  bf16x8 a[4][2], bq0[2][2], bq1[2][2];
  // prologue: tile0 (A+B) -> buf0, tile1 B -> buf1
  STAGE_HALF(A, lda, row0, 0, A0, 0);
  STAGE_HALF(A, lda, row0, 0, A0, 1);
  STAGE_HALF(B, 1024, col0, 0, B0, 0);
  STAGE_HALF(B, 1024, col0, 0, B0, 1);
  STAGE_HALF(B, 1024, col0, 64, B1, 0);
  STAGE_HALF(B, 1024, col0, 64, B1, 1);
  VM4(); BAR(); SCH0();
  for (int i = 0; i < 8; ++i) {
    const int k1 = (2 * i + 1) * 64;
    const int k2 = (2 * i + 2) * 64;
    const int k3 = (2 * i + 3) * 64;
    const bool st2 = (i < 7);   // tiles 2i+2 / 2i+3 exist
    // ---- tile 2i from buf0 ----
    // P1
    DS_A(0, A0); DS_B(0, B0, bq0);
    STAGE_HALF(A, lda, row0, k1, A1, 0);
    BAR(); LGKM0(); SCH0(); MFMA_Q(0, 0, bq0); BAR(); SCH0();
    // P2
    DS_B(1, B0, bq1);
    STAGE_HALF(A, lda, row0, k1, A1, 1);
    BAR(); LGKM0(); SCH0(); MFMA_Q(0, 1, bq1); BAR(); SCH0();
    // P3
    DS_A(1, A0);
    if (st2) STAGE_HALF(B, 1024, col0, k2, B0, 0);
    BAR(); LGKM0(); SCH0(); MFMA_Q(1, 0, bq0); BAR(); SCH0();
    // P4
    if (st2) { STAGE_HALF(B, 1024, col0, k2, B0, 1); VM4(); } else { VM0(); }
    BAR(); LGKM0(); SCH0(); MFMA_Q(1, 1, bq1); BAR(); SCH0();
    // ---- tile 2i+1 from buf1 ----
    // P5
    DS_A(0, A1); DS_B(0, B1, bq0);
    if (st2) STAGE_HALF(A, lda, row0, k2, A0, 0);
    BAR(); LGKM0(); SCH0(); MFMA_Q(0, 0, bq0); BAR(); SCH0();
    // P6
    DS_B(1, B1, bq1);
    if (st2) STAGE_HALF(A, lda, row0, k2, A0, 1);
    BAR(); LGKM0(); SCH0(); MFMA_Q(0, 1, bq1); BAR(); SCH0();
    // P7
    DS_A(1, A1);
    if (st2) STAGE_HALF(B, 1024, col0, k3, B1, 0);
    BAR(); LGKM0(); SCH0(); MFMA_Q(1, 0, bq0); BAR(); SCH0();
    // P8
    if (st2) { STAGE_HALF(B, 1024, col0, k3, B1, 1); VM4(); } else { VM0(); }
    BAR(); LGKM0(); SCH0(); MFMA_Q(1, 1, bq1); BAR(); SCH0();
  }
}

// ---------------- Bu GEMM: X @ [BreT;BimT]^T -> bf16 T x 2048 ----------------
__global__ __launch_bounds__(512, 2) void gemm_bu(
    const ushort* __restrict__ A, const ushort* __restrict__ B,
    ushort* __restrict__ O) {
  __shared__ __align__(16) ushort lds[65536];
  const int tid = threadIdx.x;
  const int w = tid >> 6, l = tid & 63;
  const int wr = w >> 2, wc = w & 3;
  const int lo = l & 15, q = l >> 4;
  const int xorv = (lo & 7) << 4;
  const int c0us = ((q * 16) ^ xorv) >> 1;
  const int c1us = ((64 + q * 16) ^ xorv) >> 1;
  const int id = blockIdx.y * 64 + blockIdx.x;
  const int nwg = 64 * (int)gridDim.y;
  const int s = (id & 7) * (nwg >> 3) + (id >> 3);   // XCD swizzle (nwg%8==0)
  const int row0 = (s & 63) * 256, col0 = (s >> 6) * 256;
  f32x4 acc[8][4];
#pragma unroll
  for (int m = 0; m < 8; ++m)
#pragma unroll
    for (int n = 0; n < 4; ++n) acc[m][n] = (f32x4){0.f, 0.f, 0.f, 0.f};
  gemm256_seg(A, 1024, B, lds, row0, col0, w, l, wr, wc, lo, q, c0us, c1us, acc);
  const int rowb = row0 + wr * 128, colb = col0 + wc * 64;
#pragma unroll
  for (int m = 0; m < 8; ++m)
#pragma unroll
    for (int n = 0; n < 4; ++n) {
      int col = colb + n * 16 + lo;
#pragma unroll
      for (int r = 0; r < 4; ++r)
        O[(size_t)(rowb + m * 16 + q * 4 + r) * 2048 + col] = f2bf(acc[m][n][r]);
    }
}

// ---------------- out = Hre@Cre^T + Him@(-Cim)^T + X@D^T ----------------
__global__ __launch_bounds__(512, 2) void gemm3(
    const ushort* __restrict__ Hall,
    const ushort* __restrict__ CreB, const ushort* __restrict__ CimB,
    const ushort* __restrict__ X,    const ushort* __restrict__ DT,
    float* __restrict__ O) {
  __shared__ __align__(16) ushort lds[65536];
  const int tid = threadIdx.x;
  const int w = tid >> 6, l = tid & 63;
  const int wr = w >> 2, wc = w & 3;
  const int lo = l & 15, q = l >> 4;
  const int xorv = (lo & 7) << 4;
  const int c0us = ((q * 16) ^ xorv) >> 1;
  const int c1us = ((64 + q * 16) ^ xorv) >> 1;
  const int id = blockIdx.y * 64 + blockIdx.x;
  const int nwg = 64 * (int)gridDim.y;
  const int s = (id & 7) * (nwg >> 3) + (id >> 3);
  const int row0 = (s & 63) * 256, col0 = (s >> 6) * 256;
  f32x4 acc[8][4];
#pragma unroll
  for (int m = 0; m < 8; ++m)
#pragma unroll
    for (int n = 0; n < 4; ++n) acc[m][n] = (f32x4){0.f, 0.f, 0.f, 0.f};
  gemm256_seg(Hall,        2048, CreB, lds, row0, col0, w, l, wr, wc, lo, q, c0us, c1us, acc);
  gemm256_seg(Hall + 1024, 2048, CimB, lds, row0, col0, w, l, wr, wc, lo, q, c0us, c1us, acc);
  gemm256_seg(X,           1024, DT,   lds, row0, col0, w, l, wr, wc, lo, q, c0us, c1us, acc);
  const int rowb = row0 + wr * 128, colb = col0 + wc * 64;
#pragma unroll
  for (int m = 0; m < 8; ++m)
#pragma unroll
    for (int n = 0; n < 4; ++n) {
      int col = colb + n * 16 + lo;
#pragma unroll
      for (int r = 0; r < 4; ++r)
        O[(size_t)(rowb + m * 16 + q * 4 + r) * HID + col] = acc[m][n][r];
    }
}

// ---------------- scan pass A: chunk sums only (Bu: T x 2048 bf16) -------------
__global__ __launch_bounds__(256) void scan_sums(
    const ushort* __restrict__ Bu,
    const float* __restrict__ lam_re, const float* __restrict__ lam_im,
    float* __restrict__ Sre, float* __restrict__ Sim) {
  int h0 = (blockIdx.y * 256 + threadIdx.x) * 2;
  int c = blockIdx.x;
  float lr0 = lam_re[h0], li0 = lam_im[h0];
  float lr1 = lam_re[h0 + 1], li1 = lam_im[h0 + 1];
  float hr0 = 0.f, hi0 = 0.f, hr1 = 0.f, hi1 = 0.f;
  const uint* P = (const uint*)Bu;
  size_t baseR = (size_t)c * CHUNK * 1024 + (h0 >> 1);          // uint idx, row stride 1024
  size_t baseI = baseR + 512;
#pragma unroll 8
  for (int t = 0; t < CHUNK; ++t) {
    uint re = P[baseR + (size_t)t * 1024];
    uint im = P[baseI + (size_t)t * 1024];
    float br0 = bf2f((ushort)re), br1 = bf2f((ushort)(re >> 16));
    float bi0 = bf2f((ushort)im), bi1 = bf2f((ushort)(im >> 16));
    float nr0 = fmaf(lr0, hr0, fmaf(-li0, hi0, br0));
    float ni0 = fmaf(lr0, hi0, fmaf(li0, hr0, bi0));
    float nr1 = fmaf(lr1, hr1, fmaf(-li1, hi1, br1));
    float ni1 = fmaf(lr1, hi1, fmaf(li1, hr1, bi1));
    hr0 = nr0; hi0 = ni0; hr1 = nr1; hi1 = ni1;
  }
  Sre[(size_t)c * HID + h0] = hr0;  Sre[(size_t)c * HID + h0 + 1] = hr1;
  Sim[(size_t)c * HID + h0] = hi0;  Sim[(size_t)c * HID + h0 + 1] = hi1;
}

// ---------------- scan pass 2: serial carry scan over chunks ----------------
__global__ __launch_bounds__(256) void scan_carry(
    const float* __restrict__ Sre, const float* __restrict__ Sim,
    const float* __restrict__ lam_re, const float* __restrict__ lam_im,
    float* __restrict__ Pre, float* __restrict__ Pim) {
  int h = blockIdx.x * 256 + threadIdx.x;
  float lr = lam_re[h], li = lam_im[h];
  float pr = lr, pi = li;       // lambda^64 via 6 squarings
#pragma unroll
  for (int s = 0; s < 6; ++s) {
    float nr = pr * pr - pi * pi;
    float ni = 2.f * pr * pi;
    pr = nr; pi = ni;
  }
  float cr = 0.f, ci = 0.f;
  for (int c = 0; c < NCHUNK; ++c) {
    Pre[(size_t)c * HID + h] = cr;
    Pim[(size_t)c * HID + h] = ci;
    float sr = Sre[(size_t)c * HID + h];
    float si = Sim[(size_t)c * HID + h];
    float nr = fmaf(pr, cr, fmaf(-pi, ci, sr));
    float ni = fmaf(pr, ci, fmaf(pi, cr, si));
    cr = nr; ci = ni;
  }
}

// ---------------- scan pass B: replay with carry init, emit bf16 Hall ----------
__global__ __launch_bounds__(256) void scan_emit(
    const ushort* __restrict__ Bu,
    const float* __restrict__ lam_re, const float* __restrict__ lam_im,
    const float* __restrict__ Pre, const float* __restrict__ Pim,
    ushort* __restrict__ Hall) {
  int h0 = (blockIdx.y * 256 + threadIdx.x) * 2;
  int c = blockIdx.x;
  float lr0 = lam_re[h0], li0 = lam_im[h0];
  float lr1 = lam_re[h0 + 1], li1 = lam_im[h0 + 1];
  float hr0 = Pre[(size_t)c * HID + h0], hi0 = Pim[(size_t)c * HID + h0];
  float hr1 = Pre[(size_t)c * HID + h0 + 1], hi1 = Pim[(size_t)c * HID + h0 + 1];
  const uint* P = (const uint*)Bu;
  uint* Q = (uint*)Hall;
  size_t baseR = (size_t)c * CHUNK * 1024 + (h0 >> 1);
  size_t baseI = baseR + 512;
#pragma unroll 8
  for (int t = 0; t < CHUNK; ++t) {
    uint re = P[baseR + (size_t)t * 1024];
    uint im = P[baseI + (size_t)t * 1024];
    float br0 = bf2f((ushort)re), br1 = bf2f((ushort)(re >> 16));
    float bi0 = bf2f((ushort)im), bi1 = bf2f((ushort)(im >> 16));
    float nr0 = fmaf(lr0, hr0, fmaf(-li0, hi0, br0));
    float ni0 = fmaf(lr0, hi0, fmaf(li0, hr0, bi0));
    float nr1 = fmaf(lr1, hr1, fmaf(-li1, hi1, br1));
    float ni1 = fmaf(lr1, hi1, fmaf(li1, hr1, bi1));
    hr0 = nr0; hi0 = ni0; hr1 = nr1; hi1 = ni1;
    Q[baseR + (size_t)t * 1024] = (uint)f2bf(hr0) | ((uint)f2bf(hr1) << 16);
    Q[baseI + (size_t)t * 1024] = (uint)f2bf(hi0) | ((uint)f2bf(hi1) << 16);
  }
}

extern "C" void kernel_launch(void* const* d_in, const int* in_sizes, int n_in,
                              void* d_out, int out_size, void* d_ws, size_t ws_size,
                              hipStream_t stream) {
  const float* inputs    = (const float*)d_in[0];
  const float* nu_log    = (const float*)d_in[1];
  const float* theta_log = (const float*)d_in[2];
  const float* gamma_log = (const float*)d_in[3];
  const float* B_re      = (const float*)d_in[4];
  const float* B_im      = (const float*)d_in[5];
  const float* C_re      = (const float*)d_in[6];
  const float* C_im      = (const float*)d_in[7];
  const float* D         = (const float*)d_in[8];
  float* out = (float*)d_out;

  char* ws = (char*)d_ws;
  constexpr size_t TH = (size_t)T_LEN * HID;       // 16.8M
  constexpr size_t W  = (size_t)1024 * 1024;
  constexpr size_t CH = (size_t)NCHUNK * HID;

  ushort* Xbf  = (ushort*)(ws);                    // TH*2
  ushort* Bu   = (ushort*)(ws + TH * 2);           // TH*2*2 (T x 2048)
  ushort* Hall = (ushort*)(ws + TH * 6);           // TH*2*2 (T x 2048)
  char*   p    = ws + TH * 10;
  ushort* Ball = (ushort*)(p);             p += 2 * W * 2;   // [BreT; BimT]
  ushort* CreB = (ushort*)(p);             p += W * 2;
  ushort* CimB = (ushort*)(p);             p += W * 2;
  ushort* DT   = (ushort*)(p);             p += W * 2;
  float*  Sre  = (float*)(p);              p += CH * 4;
  float*  Sim  = (float*)(p);              p += CH * 4;
  float*  Pre  = (float*)(p);              p += CH * 4;
  float*  Pim  = (float*)(p);              p += CH * 4;
  float*  lamR = (float*)(p);              p += 4096;
  float*  lamI = (float*)(p);              p += 4096;
  float*  eg   = (float*)(p);              p += 4096;
  ushort* BreT = Ball;
  ushort* BimT = Ball + W;

  prep_kernel<<<dim3(HID / 256), 256, 0, stream>>>(nu_log, theta_log, gamma_log,
                                                   lamR, lamI, eg);
  convX<<<dim3((unsigned)(TH / 4 / 256)), 256, 0, stream>>>(inputs, Xbf);
  weight_prep<<<dim3(32, 32, 5), 256, 0, stream>>>(B_re, B_im, C_re, C_im, D, eg,
                                                   BreT, BimT, CreB, CimB, DT);

  gemm_bu<<<dim3(T_LEN / 256, 2048 / 256), 512, 0, stream>>>(Xbf, Ball, Bu);

  scan_sums<<<dim3(NCHUNK, HID / 512), 256, 0, stream>>>(Bu, lamR, lamI, Sre, Sim);
  scan_carry<<<dim3(HID / 256), 256, 0, stream>>>(Sre, Sim, lamR, lamI, Pre, Pim);
  scan_emit<<<dim3(NCHUNK, HID / 512), 256, 0, stream>>>(Bu, lamR, lamI, Pre, Pim,
                                                         Hall);

  gemm3<<<dim3(T_LEN / 256, HID / 256), 512, 0, stream>>>(Hall, CreB, CimB, Xbf, DT,
                                                          out);
}